// Round 7
// baseline (105.306 us; speedup 1.0000x reference)
//
#include <hip/hip_runtime.h>
#include <hip/hip_bf16.h>
#include <hip/hip_fp16.h>

// minGRU parallel scan, B=4 L=8192 DX=512 DH=512.
// h_t = a_t h_{t-1} + b_t, a=sigmoid(-k), b=sigmoid(k)*g(p); linear-space chunked scan.
// R7: R6 structure + asm-pinned weight registers (defeat rematerialization; the
// R4-R6 kernels were silently reloading weights every mt iter, VGPR=108-112)
// + shfl-xor tree compose for the fused chunk aggregates (half the ds_bpermutes).

#define BB 4
#define LL 8192
#define MM (BB*LL)        // 32768 rows
#define NC 128            // chunks per batch
#define CHUNK 64          // L / NC

typedef __attribute__((ext_vector_type(8))) short bf16x8;
typedef __attribute__((ext_vector_type(4))) float f32x4;

__device__ inline unsigned f2bf(float f) {
    unsigned u = __float_as_uint(f);
    return ((u + 0x7FFFu + ((u >> 16) & 1u)) >> 16) & 0xFFFFu;
}

// f32 -> bf16, XOR chunk-swizzle baked into the GLOBAL layout (validated R2):
// 8-elem unit (seg*8+sub) of row l stored at unit seg*8 + (sub^(l&7)).
__global__ void cvt_swz(const float* __restrict__ in, unsigned short* __restrict__ out, int rows) {
    int t = blockIdx.x * 256 + threadIdx.x;
    if (t >= rows * 64) return;
    int l = t >> 6, c = t & 63;
    int seg = c >> 3, sub = c & 7;
    int q = sub ^ (l & 7);
    const float* p = in + (size_t)l * 512 + c * 8;
    float4 v0 = *(const float4*)p;
    float4 v1 = *(const float4*)(p + 4);
    uint4 o;
    o.x = f2bf(v0.x) | (f2bf(v0.y) << 16);
    o.y = f2bf(v0.z) | (f2bf(v0.w) << 16);
    o.z = f2bf(v1.x) | (f2bf(v1.y) << 16);
    o.w = f2bf(v1.z) | (f2bf(v1.w) << 16);
    *(uint4*)(out + (size_t)l * 512 + seg * 64 + q * 8) = o;
}

// Pack both weights into MFMA B-fragment order (validated R3).
__global__ void cvt_wfrag(const float* __restrict__ Wz, const float* __restrict__ Wh,
                          unsigned short* __restrict__ wzf, unsigned short* __restrict__ whf) {
    int t = blockIdx.x * 256 + threadIdx.x;    // 0..65535
    int wsel = t >> 15;
    int u = t & 32767;
    int lane = u & 63, lg = lane >> 4, lr = lane & 15;
    int nf2 = (u >> 6) & 7;
    int kk = (u >> 9) & 1;
    int ks = (u >> 10) & 7;
    int ntile = (u >> 13) & 3;
    int n = ntile * 128 + nf2 * 16 + lr;
    int k = ks * 64 + kk * 32 + lg * 8;
    const float* W = wsel ? Wh : Wz;
    unsigned short* o = wsel ? whf : wzf;
    const float* p = W + (size_t)n * 512 + k;
    float4 v0 = *(const float4*)p;
    float4 v1 = *(const float4*)(p + 4);
    uint4 ov;
    ov.x = f2bf(v0.x) | (f2bf(v0.y) << 16);
    ov.y = f2bf(v0.z) | (f2bf(v0.w) << 16);
    ov.z = f2bf(v1.x) | (f2bf(v1.y) << 16);
    ov.w = f2bf(v1.z) | (f2bf(v1.w) << 16);
    *(uint4*)(o + (size_t)u * 8) = ov;
}

#define GLDS(g, l) __builtin_amdgcn_global_load_lds( \
    (const __attribute__((address_space(1))) unsigned int*)(g), \
    (__attribute__((address_space(3))) unsigned int*)(l), 16, 0, 0)

// 8 waves x 16 n-cols = 128 cols/block; m-group = 512 rows = 8 mt-tiles of 64.
// grid 256: npart = bx>>6 (0..3), mgrp = bx&63 (sharers differ by 64 -> same XCD).
// Weights full-K pinned in 128 VGPR/wave; x double-buffered in LDS (128 KB).
__global__ __launch_bounds__(512, 2) void gemm_gate(
    const unsigned short* __restrict__ xs, const unsigned short* __restrict__ wzf,
    const unsigned short* __restrict__ whf,
    const float* __restrict__ bz, const float* __restrict__ bh,
    uint4* __restrict__ pkf, float2* __restrict__ agg)
{
    extern __shared__ char smem[];             // 2 x 65536 B
    const int tid = threadIdx.x;
    const int wid = tid >> 6, lane = tid & 63;
    const int lr = lane & 15, lg = lane >> 4;
    const int npart = blockIdx.x >> 6;
    const int mgrp  = blockIdx.x & 63;
    const int ns = npart * 8 + wid;            // n-slice 0..31 (16 cols each)

    // Weights for this n-slice, full K, both matrices: 128 VGPRs, PINNED.
    bf16x8 wz[16], wh[16];
#pragma unroll
    for (int kstep = 0; kstep < 16; ++kstep) {
        int ks = kstep >> 1, kk = kstep & 1;
        size_t fo = ((((size_t)(ns >> 3) * 8 + ks) * 2 + kk) * 8 + (ns & 7)) * 512 + lane * 8;
        wz[kstep] = *(const bf16x8*)(wzf + fo);
        wh[kstep] = *(const bf16x8*)(whf + fo);
    }
    // Opaque touch: values become unknown to the optimizer -> cannot be
    // rematerialized by reloading; must stay resident in VGPRs.
    asm volatile("" : "+v"(wz[0]), "+v"(wz[1]), "+v"(wz[2]), "+v"(wz[3]),
                      "+v"(wz[4]), "+v"(wz[5]), "+v"(wz[6]), "+v"(wz[7]));
    asm volatile("" : "+v"(wz[8]), "+v"(wz[9]), "+v"(wz[10]), "+v"(wz[11]),
                      "+v"(wz[12]), "+v"(wz[13]), "+v"(wz[14]), "+v"(wz[15]));
    asm volatile("" : "+v"(wh[0]), "+v"(wh[1]), "+v"(wh[2]), "+v"(wh[3]),
                      "+v"(wh[4]), "+v"(wh[5]), "+v"(wh[6]), "+v"(wh[7]));
    asm volatile("" : "+v"(wh[8]), "+v"(wh[9]), "+v"(wh[10]), "+v"(wh[11]),
                      "+v"(wh[12]), "+v"(wh[13]), "+v"(wh[14]), "+v"(wh[15]));

    const int h = ns * 16 + lr;
    const float bzv = bz[h], bhv = bh[h];
    const char* xbase = (const char*)xs + (size_t)mgrp * 512 * 1024;

#define STAGE(buf, mt) do { \
    _Pragma("unroll") \
    for (int p = 0; p < 8; ++p) { \
        int o = (p * 512 + tid) * 16; \
        GLDS(xbase + (size_t)(mt) * 65536 + o, smem + (buf) * 65536 + o); \
    } } while (0)

    STAGE(0, 0);
    __syncthreads();

    for (int mt = 0; mt < 8; ++mt) {
        const int cur = mt & 1;
        if (mt < 7) STAGE(cur ^ 1, mt + 1);    // issue early; drained by end barrier

        f32x4 acck[4] = {{0.f,0.f,0.f,0.f},{0.f,0.f,0.f,0.f},{0.f,0.f,0.f,0.f},{0.f,0.f,0.f,0.f}};
        f32x4 accp[4] = {{0.f,0.f,0.f,0.f},{0.f,0.f,0.f,0.f},{0.f,0.f,0.f,0.f},{0.f,0.f,0.f,0.f}};
        const char* lb = smem + cur * 65536;   // [64 rows][1024 B], pre-swizzled

        // A-frag read: row r=mf*16+lr, unit q=(kstep*4+lg)^(lr&7).
        bf16x8 af[2][4];
#pragma unroll
        for (int mf = 0; mf < 4; ++mf)
            af[0][mf] = *(const bf16x8*)(lb + (mf * 16 + lr) * 1024 + ((0 * 4 + lg) ^ (lr & 7)) * 16);
#pragma unroll
        for (int kstep = 0; kstep < 16; ++kstep) {
            const int sl = kstep & 1;
            if (kstep < 15) {
#pragma unroll
                for (int mf = 0; mf < 4; ++mf)
                    af[sl ^ 1][mf] = *(const bf16x8*)(lb + (mf * 16 + lr) * 1024
                                        + (((kstep + 1) * 4 + lg) ^ (lr & 7)) * 16);
            }
#pragma unroll
            for (int mf = 0; mf < 4; ++mf) {
                acck[mf] = __builtin_amdgcn_mfma_f32_16x16x32_bf16(af[sl][mf], wz[kstep], acck[mf], 0, 0, 0);
                accp[mf] = __builtin_amdgcn_mfma_f32_16x16x32_bf16(af[sl][mf], wh[kstep], accp[mf], 0, 0, 0);
            }
        }

        // Epilogue: C/D layout col=lane&15, row=(lane>>4)*4+j [m89-verified].
        // This mt-tile is exactly chunk cg = mgrp*8 + mt.
        const int cg = mgrp * 8 + mt;
        float Acomb = 1.f, Bcomb = 0.f;
#pragma unroll
        for (int mf = 0; mf < 4; ++mf) {
            float As = 1.f, Bs = 0.f;
            uint4 ov;
#pragma unroll
            for (int j = 0; j < 4; ++j) {
                float kv = acck[mf][j] + bzv;
                float pv = accp[mf][j] + bhv;
                float av = 1.0f / (1.0f + __expf(kv));           // 1-z = sigmoid(-k)
                float zv = 1.0f - av;
                float gv = (pv >= 0.0f) ? (pv + 0.5f) : (1.0f / (1.0f + __expf(-pv)));
                float bvv = zv * gv;
                __half2 hp = __floats2half2_rn(av, bvv);
                ((unsigned*)&ov)[j] = *(unsigned*)&hp;
                Bs = fmaf(av, Bs, bvv);
                As *= av;
            }
            pkf[((size_t)cg * 32 + ns) * 4 * 64 + (size_t)mf * 64 + lane] = ov;
            // tree compose across the 4 lane-groups (time order lg=0..3):
            // step 1: xor 16 (pair compose), step 2: xor 32. later∘earlier =
            // (A_l*A_e, A_l*B_e + B_l); parity of lg picks operand roles.
            float pa = __shfl_xor(As, 16, 64);
            float pb = __shfl_xor(Bs, 16, 64);
            float A1 = As * pa;
            float B1 = (lg & 1) ? fmaf(As, pb, Bs) : fmaf(pa, Bs, pb);
            float pa2 = __shfl_xor(A1, 32, 64);
            float pb2 = __shfl_xor(B1, 32, 64);
            float Ag = A1 * pa2;
            float Bg = (lg & 2) ? fmaf(A1, pb2, B1) : fmaf(pa2, B1, pb2);
            Bcomb = fmaf(Ag, Bcomb, Bg);
            Acomb *= Ag;
        }
        if (lg == 0)
            agg[(size_t)cg * 512 + h] = make_float2(Acomb, Bcomb);

        __syncthreads();   // next buffer staged; all reads of cur done
    }
}

// Phase 2: sequential scan over chunk aggregates, emitting carry-in per chunk.
__global__ void scan_p2(const float* __restrict__ h0, const float2* __restrict__ agg,
                        float* __restrict__ carry) {
    int g = blockIdx.x * 256 + threadIdx.x;   // 0..2047
    int b = g >> 9, h = g & 511;
    float v = h0[b * 512 + h];
    float s = (v >= 0.f) ? (v + 0.5f) : (1.f / (1.f + __expf(-v)));   // g(h_0)
    for (int c = 0; c < NC; ++c) {
        size_t o = ((size_t)(b * NC + c)) * 512 + h;
        carry[o] = s;
        float2 ab = agg[o];
        s = fmaf(ab.x, s, ab.y);
    }
}

// Phase 3: replay recurrence within chunk from frag-ordered half2 (a,b), write h.
__global__ void scan_p3(const float* __restrict__ carry, const uint4* __restrict__ pkf,
                        float* __restrict__ out) {
    int c = blockIdx.x, b = blockIdx.y;
    int tid = threadIdx.x;
    int lr = tid & 15, nsl = (tid >> 4) & 3, w = tid >> 6;
    int nsa = w * 4 + nsl, nsb = nsa + 16;
    int ha = nsa * 16 + lr, hb = ha + 256;
    int cg = b * NC + c;
    size_t co = (size_t)cg * 512;
    float s0 = carry[co + ha], s1 = carry[co + hb];
    size_t cb = (size_t)cg * 8192;            // uint4 units: 32 ns * 4 mf * 64 lanes
    size_t ob = (size_t)cg * 64 * 512;        // == (b*LL + c*64)*512
#pragma unroll
    for (int mf = 0; mf < 4; ++mf) {
#pragma unroll
        for (int lg = 0; lg < 4; ++lg) {
            uint4 fa = pkf[cb + ((size_t)nsa * 4 + mf) * 64 + lg * 16 + lr];
            uint4 fb = pkf[cb + ((size_t)nsb * 4 + mf) * 64 + lg * 16 + lr];
#pragma unroll
            for (int j = 0; j < 4; ++j) {
                int t = mf * 16 + lg * 4 + j;
                unsigned ua = ((unsigned*)&fa)[j];
                unsigned ub = ((unsigned*)&fb)[j];
                float2 ab0 = __half22float2(*(__half2*)&ua);
                float2 ab1 = __half22float2(*(__half2*)&ub);
                s0 = fmaf(ab0.x, s0, ab0.y);
                s1 = fmaf(ab1.x, s1, ab1.y);
                out[ob + (size_t)t * 512 + ha] = s0;
                out[ob + (size_t)t * 512 + hb] = s1;
            }
        }
    }
}

extern "C" void kernel_launch(void* const* d_in, const int* in_sizes, int n_in,
                              void* d_out, int out_size, void* d_ws, size_t ws_size,
                              hipStream_t stream) {
    const float* x  = (const float*)d_in[0];
    const float* h0 = (const float*)d_in[1];
    const float* Wz = (const float*)d_in[2];
    const float* bz = (const float*)d_in[3];
    const float* Wh = (const float*)d_in[4];
    const float* bh = (const float*)d_in[5];
    float* out = (float*)d_out;

    // workspace layout (~100 MB)
    unsigned short* xs  = (unsigned short*)d_ws;                 // 32 MB (row-major swizzled)
    unsigned short* wzf = xs + (size_t)MM * 512;                 // 0.5 MB
    unsigned short* whf = wzf + (size_t)512 * 512;               // 0.5 MB
    uint4* pkf   = (uint4*)(whf + (size_t)512 * 512);            // 64 MB
    float2* agg  = (float2*)((char*)pkf + (size_t)MM * 512 * 4); // 2 MB
    float* carry = (float*)(agg + (size_t)BB * NC * 512);        // 1 MB

    cvt_swz<<<8192, 256, 0, stream>>>(x, xs, MM);
    cvt_wfrag<<<256, 256, 0, stream>>>(Wz, Wh, wzf, whf);
    gemm_gate<<<256, 512, 131072, stream>>>(xs, wzf, whf, bz, bh, pkf, agg);
    scan_p2<<<8, 256, 0, stream>>>(h0, agg, carry);
    scan_p3<<<dim3(NC, BB), 256, 0, stream>>>(carry, pkf, out);
}